// Round 7
// baseline (2714.588 us; speedup 1.0000x reference)
//
#include <hip/hip_runtime.h>
#include <hip/hip_bf16.h>
#include <stdint.h>

// a3c_lstm_ga forward, MI355X. Float tensors f32 (bf16-rounded values), ints
// int32. Output f32: [critic(1), actor(4), hx_new(768), cx_new(768)].
// Bug-faithful: only attn[0] consumed -> one GRU scan.
//
// R7: MFMA scan, 3 waves/SIMD + conflict-free LDS. R6 (2 waves/SIMD) hit
// 2707 cyc/step = 1536 MFMA floor (96 x 16x16x32_f16 per SIMD) + ~1170
// bubbles; SQ_LDS_BANK_CONFLICT showed 256 cyc/step from hhi/hlo bank
// aliasing. Now: 768 thr / 12 waves / waves_per_eu(3,3); wave owns 64 rows
// = 4 N-tiles x 8 K-tiles = 32 laundered B-frags (128 regs) + 16 acc.
// h LDS layout interleaves hi/lo in 128B chunks: chunk c = hi[32c..32c+31]
// (64B, banks 0-15) then lo[32c..32c+31] (64B, banks 16-31) -> each A-read
// hits all 32 banks exactly once. h rides A rows 0/1 (hi, (h-hi)*1024);
// y = D[0][n] + D[1][n]/1024.

typedef _Float16 half8 __attribute__((ext_vector_type(8)));
typedef _Float16 half2v __attribute__((ext_vector_type(2)));
typedef float f32x4 __attribute__((ext_vector_type(4)));

__device__ __forceinline__ float sigm(float x) { return 1.0f / (1.0f + __expf(-x)); }
__device__ __forceinline__ float tanh_f(float x) { return 2.0f / (1.0f + __expf(-2.0f * x)) - 1.0f; }

// ---------------- pack W_hh f32 -> f16 pairs ----------------
__global__ void k_pack(const float* __restrict__ whh, uint32_t* __restrict__ wf16p) {
    int i = blockIdx.x * 256 + threadIdx.x;  // 98304 pairs
    if (i >= 98304) return;
    half2v p = {(_Float16)whh[2 * i], (_Float16)whh[2 * i + 1]};
    wf16p[i] = __builtin_bit_cast(uint32_t, p);
}

// ---------------- conv tower ----------------
__global__ void k_conv1(const float* __restrict__ x, const float* __restrict__ w,
                        const float* __restrict__ b, float* __restrict__ h1) {
    int idx = blockIdx.x * 256 + threadIdx.x;
    if (idx >= 128 * 30 * 30) return;
    int ox = idx % 30, oy = (idx / 30) % 30, oc = idx / 900;
    const float* wr = w + oc * 192;
    float acc = b[oc];
    for (int c = 0; c < 3; ++c)
        for (int ky = 0; ky < 8; ++ky) {
            const float* xr = x + (c * 124 + oy * 4 + ky) * 124 + ox * 4;
            const float* wk = wr + (c * 8 + ky) * 8;
#pragma unroll
            for (int kx = 0; kx < 8; ++kx) acc = fmaf(xr[kx], wk[kx], acc);
        }
    h1[idx] = fmaxf(acc, 0.0f);
}

__global__ void k_conv2(const float* __restrict__ h1, const float* __restrict__ w,
                        const float* __restrict__ b, float* __restrict__ h2) {
    int idx = blockIdx.x * 256 + threadIdx.x;
    if (idx >= 64 * 14 * 14) return;
    int ox = idx % 14, oy = (idx / 14) % 14, oc = idx / 196;
    float acc = b[oc];
    const float* wr = w + oc * 128 * 16;
    for (int c = 0; c < 128; ++c) {
#pragma unroll
        for (int ky = 0; ky < 4; ++ky) {
            const float* hr = h1 + (c * 30 + oy * 2 + ky) * 30 + ox * 2;
            const float* wk = wr + (c * 4 + ky) * 4;
#pragma unroll
            for (int kx = 0; kx < 4; ++kx) acc = fmaf(hr[kx], wk[kx], acc);
        }
    }
    h2[idx] = fmaxf(acc, 0.0f);
}

__global__ void k_conv3(const float* __restrict__ h2, const float* __restrict__ w,
                        const float* __restrict__ b, float* __restrict__ x3) {
    int idx = blockIdx.x * 256 + threadIdx.x;
    if (idx >= 64 * 6 * 6) return;
    int ox = idx % 6, oy = (idx / 6) % 6, oc = idx / 36;
    float acc = b[oc];
    const float* wr = w + oc * 64 * 16;
    for (int c = 0; c < 64; ++c) {
#pragma unroll
        for (int ky = 0; ky < 4; ++ky) {
            const float* hr = h2 + (c * 14 + oy * 2 + ky) * 14 + ox * 2;
            const float* wk = wr + (c * 4 + ky) * 4;
#pragma unroll
            for (int kx = 0; kx < 4; ++kx) acc = fmaf(hr[kx], wk[kx], acc);
        }
    }
    x3[idx] = fmaxf(acc, 0.0f);
}

// ---------------- GRU input-gate precompute ----------------
__global__ void k_gi(const int* __restrict__ curr, const float* __restrict__ emb,
                     const float* __restrict__ wih, const float* __restrict__ bih,
                     float* __restrict__ gi) {
    int idx = blockIdx.x * 256 + threadIdx.x;  // 2048*768
    int j = idx % 768, t = idx / 768;
    int tok = curr[t];
    const float4* e = (const float4*)(emb + tok * 32);
    const float4* wr = (const float4*)(wih + j * 32);
    float acc = bih[j];
#pragma unroll
    for (int k = 0; k < 8; ++k) {
        float4 ev = e[k], wv = wr[k];
        acc = fmaf(ev.x, wv.x, acc);
        acc = fmaf(ev.y, wv.y, acc);
        acc = fmaf(ev.z, wv.z, acc);
        acc = fmaf(ev.w, wv.w, acc);
    }
    gi[idx] = acc;
}

// ---------------- MFMA GRU scan: 768 thr, 12 waves, 3 waves/SIMD ---------------
#define FOR8(X, nt) X(nt, 0) X(nt, 1) X(nt, 2) X(nt, 3) X(nt, 4) X(nt, 5) X(nt, 6) X(nt, 7)
#define FOR4(Y) Y(0) Y(1) Y(2) Y(3)

#define DECLB(nt, kt) uint4 b##nt##_##kt;
#define DECLBROW(nt) FOR8(DECLB, nt)
#define LOADB(nt, kt) b##nt##_##kt = wp4[nt * 512 + kt * 4 + quad];
#define LOADBROW(nt) FOR8(LOADB, nt)
#define TIEB(nt, kt) \
    asm volatile("" : "+v"(b##nt##_##kt.x), "+v"(b##nt##_##kt.y), "+v"(b##nt##_##kt.z), "+v"(b##nt##_##kt.w));
#define TIEBROW(nt) FOR8(TIEB, nt)
#define DECLBIAS(nt) const float bias##nt = bhh[wbase + nt * 16 + n16];
#define DECLACC(nt) f32x4 acc##nt;
#define ZEROACC(nt) acc##nt = (f32x4)(0.0f);
#define MF(nt, kt) \
    acc##nt = __builtin_amdgcn_mfma_f32_16x16x32_f16(a##kt, __builtin_bit_cast(half8, b##nt##_##kt), acc##nt, 0, 0, 0);
#define MFK(kt) MF(0, kt) MF(1, kt) MF(2, kt) MF(3, kt)
#define LOADA(kt) half8 a##kt = __builtin_bit_cast(half8, abase[kt * 8 + quad]);
#define EPI(nt) \
    if (lane < 16) gh[wbase + nt * 16 + lane] = acc##nt.x + acc##nt.y * 0.0009765625f + bias##nt;

__global__ __attribute__((amdgpu_flat_work_group_size(768, 768), amdgpu_waves_per_eu(3, 3)))
void k_gru_scan(const float* __restrict__ gi, const uint32_t* __restrict__ wf16p,
                const float* __restrict__ bhh, const float* __restrict__ attn_w,
                const float* __restrict__ attn_b, float* __restrict__ attn0) {
    // chunk c (c=0..7): hbuf[64c..64c+31] = h_hi[32c..], hbuf[64c+32..64c+63] = h_lo[32c..]
    __shared__ __align__(16) _Float16 hbuf[512];
    __shared__ float gh[768];
    const int tid = threadIdx.x;   // 0..767
    const int lane = tid & 63;
    const int wv = tid >> 6;       // wave 0..11
    const int n16 = lane & 15;     // B col (output row-in-tile); also A row m
    const int quad = lane >> 4;    // k-subchunk selector
    const int wbase = wv * 64;     // this wave's first output row

    // B-frags: lane holds W[wbase + nt*16 + n16][kt*32 + quad*8 + j], j=0..7
    FOR4(DECLBROW)
    {
        const uint4* wp4 = (const uint4*)(wf16p + (size_t)(wbase + n16) * 128);
        FOR4(LOADBROW)
    }
    FOR4(TIEBROW)  // launder: cannot be rematerialized by re-loading
    FOR4(DECLBIAS)
    FOR4(DECLACC)

    float h_own = 0.0f;  // thread tid<256 owns h[tid]
    if (tid < 512) hbuf[tid] = (_Float16)0.0f;
    float gv0 = 0.f, gv1 = 0.f, gv2 = 0.f;
    if (tid < 256) {
        gv0 = gi[tid];
        gv1 = gi[256 + tid];
        gv2 = gi[512 + tid];
    }
    __syncthreads();

    // A-read base: n16==1 lanes read the lo half-chunk (banks 16-31), others hi
    const uint4* abase = (const uint4*)hbuf + ((n16 == 1) ? 4 : 0);
    const int hwc = (tid >> 5) * 64 + (tid & 31);  // gate-phase write index (hi)

#pragma clang loop unroll(disable)
    for (int step = 0; step < 2048; ++step) {
        // prefetch next step's input gates; latency hides under MFMAs
        float gn0 = 0.f, gn1 = 0.f, gn2 = 0.f;
        if (step < 2047 && tid < 256) {
            const float* gp = gi + (size_t)(step + 1) * 768 + tid;
            gn0 = gp[0]; gn1 = gp[256]; gn2 = gp[512];
        }

        FOR4(ZEROACC)
        // A-frag loads interleaved with the MFMA stream
        LOADA(0) LOADA(1)
        MFK(0)
        LOADA(2)
        MFK(1)
        LOADA(3)
        MFK(2)
        LOADA(4)
        MFK(3)
        LOADA(5)
        MFK(4)
        LOADA(6)
        MFK(5)
        LOADA(7)
        MFK(6)
        MFK(7)

        // y[wbase+nt*16+col] = D[0][col] + D[1][col]/1024 + bhh  (lanes 0-15)
        FOR4(EPI)
        __syncthreads();

        // gate math: thread tid<256 handles element tid
        if (tid < 256) {
            float r = sigm(gv0 + gh[tid]);
            float z = sigm(gv1 + gh[256 + tid]);
            float n = tanh_f(fmaf(r, gh[512 + tid], gv2));
            h_own = fmaf(z, h_own - n, n);  // (1-z)*n + z*h
            _Float16 hi16 = (_Float16)h_own;
            hbuf[hwc] = hi16;
            hbuf[hwc + 32] = (_Float16)((h_own - (float)hi16) * 1024.0f);
        }
        gv0 = gn0; gv1 = gn1; gv2 = gn2;
        __syncthreads();
    }

    // fused attention head: attn0[j] = sigm(attn_w[j] . h + attn_b[j]), j<64
    if (tid < 64) {
        const float* ar = attn_w + tid * 256;
        float acc = attn_b[tid];
        for (int k = 0; k < 256; ++k) {
            int c = k >> 5, i = k & 31;
            float hk = (float)hbuf[c * 64 + i] + (float)hbuf[c * 64 + 32 + i] * 0.0009765625f;
            acc = fmaf(ar[k], hk, acc);
        }
        attn0[tid] = sigm(acc);
    }
}

// ---------------- fuse + linear ----------------
__global__ void k_feat(const float* __restrict__ x3, const float* __restrict__ attn0,
                       const float* __restrict__ lw, const float* __restrict__ lb,
                       float* __restrict__ feat) {
    __shared__ __align__(16) float fused[2304];
    int t = threadIdx.x;  // 64
    for (int i = t; i < 2304; i += 64) fused[i] = x3[i] * attn0[i / 36];
    __syncthreads();
    int row = blockIdx.x * 64 + t;
    const float4* wvv = (const float4*)(lw + (size_t)row * 2304);
    float acc = lb[row];
    for (int i = 0; i < 576; ++i) {
        float4 v = wvv[i];
        const float* f = fused + i * 4;
        acc = fmaf(v.x, f[0], acc);
        acc = fmaf(v.y, f[1], acc);
        acc = fmaf(v.z, f[2], acc);
        acc = fmaf(v.w, f[3], acc);
    }
    feat[row] = fmaxf(acc, 0.0f);
}

// ---------------- LSTM gates ----------------
__global__ void k_lstm_gates(const float* __restrict__ wih, const float* __restrict__ whh,
                             const float* __restrict__ bih, const float* __restrict__ bhh,
                             const float* __restrict__ hx, const float* __restrict__ feat,
                             float* __restrict__ gates) {
    int wid = threadIdx.x >> 6, lane = threadIdx.x & 63;
    int row = blockIdx.x * 4 + wid;
    const float* wi = wih + (size_t)row * 768;
    const float* wh = whh + (size_t)row * 768;
    float acc = 0.0f;
#pragma unroll
    for (int i = 0; i < 12; ++i) {
        int k = lane + i * 64;
        acc = fmaf(wi[k], feat[k & 255], acc);
        acc = fmaf(wh[k], hx[k], acc);
    }
#pragma unroll
    for (int s = 32; s; s >>= 1) acc += __shfl_down(acc, s, 64);
    if (lane == 0) gates[row] = acc + bih[row] + bhh[row];
}

// ---------------- LSTM cell ----------------
__global__ void k_lstm_cell(const float* __restrict__ gates, const float* __restrict__ cx,
                            float* __restrict__ out, float* __restrict__ hxf) {
    int i = threadIdx.x;  // 768
    float g_i = gates[i], g_f = gates[768 + i], g_g = gates[1536 + i], g_o = gates[2304 + i];
    float c = cx[i];
    float cn = sigm(g_f) * c + sigm(g_i) * tanh_f(g_g);
    float hn = sigm(g_o) * tanh_f(cn);
    out[5 + i] = hn;
    out[5 + 768 + i] = cn;
    hxf[i] = hn;
}

// ---------------- heads ----------------
__global__ void k_heads(const float* __restrict__ hxf, const float* __restrict__ temb,
                        const int* __restrict__ tx, const float* __restrict__ cw,
                        const float* __restrict__ cb, const float* __restrict__ aw,
                        const float* __restrict__ ab, float* __restrict__ out) {
    __shared__ float z[800];
    int t = threadIdx.x;  // 320
    for (int i = t; i < 768; i += 320) z[i] = hxf[i];
    if (t < 32) z[768 + t] = temb[tx[0] * 32 + t];
    __syncthreads();
    int w = t >> 6, lane = t & 63;
    const float* row = (w == 0) ? cw : (aw + (size_t)(w - 1) * 800);
    float acc = 0.0f;
    for (int k = lane; k < 800; k += 64) acc = fmaf(row[k], z[k], acc);
#pragma unroll
    for (int s = 32; s; s >>= 1) acc += __shfl_down(acc, s, 64);
    if (lane == 0) {
        float b = (w == 0) ? cb[0] : ab[w - 1];
        out[w] = acc + b;
    }
}

extern "C" void kernel_launch(void* const* d_in, const int* in_sizes, int n_in,
                              void* d_out, int out_size, void* d_ws, size_t ws_size,
                              hipStream_t stream) {
    const float* x = (const float*)d_in[0];
    const int* curr = (const int*)d_in[1];
    const int* tx = (const int*)d_in[4];
    const float* hx = (const float*)d_in[5];
    const float* cx = (const float*)d_in[6];
    const float* c1w = (const float*)d_in[7];
    const float* c1b = (const float*)d_in[8];
    const float* c2w = (const float*)d_in[9];
    const float* c2b = (const float*)d_in[10];
    const float* c3w = (const float*)d_in[11];
    const float* c3b = (const float*)d_in[12];
    const float* emb = (const float*)d_in[13];
    const float* temb = (const float*)d_in[14];
    const float* gwih = (const float*)d_in[15];
    const float* gwhh = (const float*)d_in[16];
    const float* gbih = (const float*)d_in[17];
    const float* gbhh = (const float*)d_in[18];
    const float* attw = (const float*)d_in[19];
    const float* attb = (const float*)d_in[20];
    const float* linw = (const float*)d_in[21];
    const float* linb = (const float*)d_in[22];
    const float* lwih = (const float*)d_in[23];
    const float* lwhh = (const float*)d_in[24];
    const float* lbih = (const float*)d_in[25];
    const float* lbhh = (const float*)d_in[26];
    const float* cw = (const float*)d_in[27];
    const float* cb = (const float*)d_in[28];
    const float* aw = (const float*)d_in[29];
    const float* ab = (const float*)d_in[30];
    float* out = (float*)d_out;

    char* ws = (char*)d_ws;
    float* gi = (float*)(ws + 0);                 // 2048*768 f32
    float* h1 = (float*)(ws + 6291456);
    float* h2 = (float*)(ws + 6752256);
    float* x3 = (float*)(ws + 6802432);
    float* attn0 = (float*)(ws + 6811648);
    float* feat = (float*)(ws + 6811904);
    float* gates = (float*)(ws + 6812928);
    float* hxf = (float*)(ws + 6825216);
    uint32_t* wf16p = (uint32_t*)(ws + 6828288);  // 98304 u32 (f16-pair W_hh)

    k_pack<<<384, 256, 0, stream>>>(gwhh, wf16p);
    k_gi<<<6144, 256, 0, stream>>>(curr, emb, gwih, gbih, gi);
    k_conv1<<<450, 256, 0, stream>>>(x, c1w, c1b, h1);
    k_conv2<<<49, 256, 0, stream>>>(h1, c2w, c2b, h2);
    k_conv3<<<9, 256, 0, stream>>>(h2, c3w, c3b, x3);
    k_gru_scan<<<1, 768, 0, stream>>>(gi, wf16p, gbhh, attw, attb, attn0);
    k_feat<<<4, 64, 0, stream>>>(x3, attn0, linw, linb, feat);
    k_lstm_gates<<<768, 256, 0, stream>>>(lwih, lwhh, lbih, lbhh, hx, feat, gates);
    k_lstm_cell<<<1, 768, 0, stream>>>(gates, cx, out, hxf);
    k_heads<<<1, 320, 0, stream>>>(hxf, temb, tx, cw, cb, aw, ab, out);
}

// Round 8
// 2670.633 us; speedup vs baseline: 1.0165x; 1.0165x over previous
//
#include <hip/hip_runtime.h>
#include <hip/hip_bf16.h>
#include <stdint.h>

// a3c_lstm_ga forward, MI355X. Float tensors f32 (bf16-rounded values), ints
// int32. Output f32: [critic(1), actor(4), hx_new(768), cx_new(768)].
// Bug-faithful: only attn[0] consumed -> one GRU scan.
//
// R8: gate-aligned MFMA scan, ONE barrier/step. R6/R7 burned ~1200-1350
// cyc/step on 2 barriers + a 4-wave serial gate phase (r,z,n rows scattered
// across waves forced a gh LDS round-trip). Now wave wv owns rows
// {wv*32..+31} + 256 and +512 offsets = r,z,n of ITS 32 elements as
// 6 N-tiles x 8 K-tiles = 48 MFMAs (register budget proven by R6). Gate
// math runs in-register on lanes 0-15 of every wave in parallel; hbuf is
// double-buffered by step parity -> single __syncthreads per step.
// h rides A rows 0/1 (hi, (h-hi)*1024); y = D[0][n] + D[1][n]/1024.
// r/z biases folded into gi by k_gi; n-bias kept (scaled by r).

typedef _Float16 half8 __attribute__((ext_vector_type(8)));
typedef _Float16 half2v __attribute__((ext_vector_type(2)));
typedef float f32x4 __attribute__((ext_vector_type(4)));

__device__ __forceinline__ float sigm(float x) { return 1.0f / (1.0f + __expf(-x)); }
__device__ __forceinline__ float tanh_f(float x) { return 2.0f / (1.0f + __expf(-2.0f * x)) - 1.0f; }

// ---------------- pack W_hh f32 -> f16 pairs ----------------
__global__ void k_pack(const float* __restrict__ whh, uint32_t* __restrict__ wf16p) {
    int i = blockIdx.x * 256 + threadIdx.x;  // 98304 pairs
    if (i >= 98304) return;
    half2v p = {(_Float16)whh[2 * i], (_Float16)whh[2 * i + 1]};
    wf16p[i] = __builtin_bit_cast(uint32_t, p);
}

// ---------------- conv tower ----------------
__global__ void k_conv1(const float* __restrict__ x, const float* __restrict__ w,
                        const float* __restrict__ b, float* __restrict__ h1) {
    int idx = blockIdx.x * 256 + threadIdx.x;
    if (idx >= 128 * 30 * 30) return;
    int ox = idx % 30, oy = (idx / 30) % 30, oc = idx / 900;
    const float* wr = w + oc * 192;
    float acc = b[oc];
    for (int c = 0; c < 3; ++c)
        for (int ky = 0; ky < 8; ++ky) {
            const float* xr = x + (c * 124 + oy * 4 + ky) * 124 + ox * 4;
            const float* wk = wr + (c * 8 + ky) * 8;
#pragma unroll
            for (int kx = 0; kx < 8; ++kx) acc = fmaf(xr[kx], wk[kx], acc);
        }
    h1[idx] = fmaxf(acc, 0.0f);
}

__global__ void k_conv2(const float* __restrict__ h1, const float* __restrict__ w,
                        const float* __restrict__ b, float* __restrict__ h2) {
    int idx = blockIdx.x * 256 + threadIdx.x;
    if (idx >= 64 * 14 * 14) return;
    int ox = idx % 14, oy = (idx / 14) % 14, oc = idx / 196;
    float acc = b[oc];
    const float* wr = w + oc * 128 * 16;
    for (int c = 0; c < 128; ++c) {
#pragma unroll
        for (int ky = 0; ky < 4; ++ky) {
            const float* hr = h1 + (c * 30 + oy * 2 + ky) * 30 + ox * 2;
            const float* wk = wr + (c * 4 + ky) * 4;
#pragma unroll
            for (int kx = 0; kx < 4; ++kx) acc = fmaf(hr[kx], wk[kx], acc);
        }
    }
    h2[idx] = fmaxf(acc, 0.0f);
}

__global__ void k_conv3(const float* __restrict__ h2, const float* __restrict__ w,
                        const float* __restrict__ b, float* __restrict__ x3) {
    int idx = blockIdx.x * 256 + threadIdx.x;
    if (idx >= 64 * 6 * 6) return;
    int ox = idx % 6, oy = (idx / 6) % 6, oc = idx / 36;
    float acc = b[oc];
    const float* wr = w + oc * 64 * 16;
    for (int c = 0; c < 64; ++c) {
#pragma unroll
        for (int ky = 0; ky < 4; ++ky) {
            const float* hr = h2 + (c * 14 + oy * 2 + ky) * 14 + ox * 2;
            const float* wk = wr + (c * 4 + ky) * 4;
#pragma unroll
            for (int kx = 0; kx < 4; ++kx) acc = fmaf(hr[kx], wk[kx], acc);
        }
    }
    x3[idx] = fmaxf(acc, 0.0f);
}

// ---------------- GRU input-gate precompute (+ b_hh fold for r,z rows) ---------
__global__ void k_gi(const int* __restrict__ curr, const float* __restrict__ emb,
                     const float* __restrict__ wih, const float* __restrict__ bih,
                     const float* __restrict__ bhh, float* __restrict__ gi) {
    int idx = blockIdx.x * 256 + threadIdx.x;  // 2048*768
    int j = idx % 768, t = idx / 768;
    int tok = curr[t];
    const float4* e = (const float4*)(emb + tok * 32);
    const float4* wr = (const float4*)(wih + j * 32);
    float acc = bih[j] + (j < 512 ? bhh[j] : 0.0f);  // n-row bias NOT additive (r*b)
#pragma unroll
    for (int k = 0; k < 8; ++k) {
        float4 ev = e[k], wv = wr[k];
        acc = fmaf(ev.x, wv.x, acc);
        acc = fmaf(ev.y, wv.y, acc);
        acc = fmaf(ev.z, wv.z, acc);
        acc = fmaf(ev.w, wv.w, acc);
    }
    gi[idx] = acc;
}

// ---------------- MFMA GRU scan: 512 thr, 8 waves, 2/SIMD, 1 barrier/step ------
#define DECLBT(T) uint4 b##T##_0, b##T##_1, b##T##_2, b##T##_3, b##T##_4, b##T##_5, b##T##_6, b##T##_7;
#define LOADBK(T, kt, off) b##T##_##kt = wpR[(off) + (kt)*4 + quad];
#define LOADBT(T, off) LOADBK(T, 0, off) LOADBK(T, 1, off) LOADBK(T, 2, off) LOADBK(T, 3, off) \
                       LOADBK(T, 4, off) LOADBK(T, 5, off) LOADBK(T, 6, off) LOADBK(T, 7, off)
#define TIEBK(T, kt) \
    asm volatile("" : "+v"(b##T##_##kt.x), "+v"(b##T##_##kt.y), "+v"(b##T##_##kt.z), "+v"(b##T##_##kt.w));
#define TIEBT(T) TIEBK(T, 0) TIEBK(T, 1) TIEBK(T, 2) TIEBK(T, 3) TIEBK(T, 4) TIEBK(T, 5) TIEBK(T, 6) TIEBK(T, 7)
#define MF1(T, kt, areg) \
    acc##T = __builtin_amdgcn_mfma_f32_16x16x32_f16(areg, __builtin_bit_cast(half8, b##T##_##kt), acc##T, 0, 0, 0);
#define MFK(kt, areg) MF1(0, kt, areg) MF1(1, kt, areg) MF1(2, kt, areg) \
                      MF1(3, kt, areg) MF1(4, kt, areg) MF1(5, kt, areg)

__global__ __attribute__((amdgpu_flat_work_group_size(512, 512), amdgpu_waves_per_eu(2, 2)))
void k_gru_scan(const float* __restrict__ gi, const uint32_t* __restrict__ wf16p,
                const float* __restrict__ bhh, const float* __restrict__ attn_w,
                const float* __restrict__ attn_b, float* __restrict__ attn0) {
    // double-buffered h: buf p at [p*512, p*512+512); chunk c = hi[32c..]+lo[32c..]
    __shared__ __align__(16) _Float16 hbuf[1024];
    const int tid = threadIdx.x;   // 0..511
    const int lane = tid & 63;
    const int wv = tid >> 6;       // wave 0..7; owns elements [wv*32, wv*32+32)
    const int n16 = lane & 15;     // B row-in-tile; A row m; gate col
    const int quad = lane >> 4;    // k-subchunk
    const int li = n16;            // load index (all lanes, safe)

    // B-frags: tiles T0/T1 = r rows wv*32(+16), T2/T3 = z (+256), T4/T5 = n (+512)
    DECLBT(0) DECLBT(1) DECLBT(2) DECLBT(3) DECLBT(4) DECLBT(5)
    {
        const uint4* wpR = (const uint4*)wf16p + (size_t)(wv * 32 + n16) * 32;
        LOADBT(0, 0) LOADBT(1, 512) LOADBT(2, 8192) LOADBT(3, 8704) LOADBT(4, 16384) LOADBT(5, 16896)
    }
    TIEBT(0) TIEBT(1) TIEBT(2) TIEBT(3) TIEBT(4) TIEBT(5)

    // per-lane gate state (valid in lanes 0-15)
    const float bn0 = bhh[512 + wv * 32 + li];
    const float bn1 = bhh[512 + wv * 32 + 16 + li];
    float gr0, gr1, gz0, gz1, gn0v, gn1v;
    {
        const float* g0 = gi + wv * 32 + li;
        gr0 = g0[0]; gr1 = g0[16]; gz0 = g0[256]; gz1 = g0[272]; gn0v = g0[512]; gn1v = g0[528];
    }
    float h0 = 0.0f, h1 = 0.0f;
    hbuf[tid] = (_Float16)0.0f;
    hbuf[512 + tid] = (_Float16)0.0f;
    __syncthreads();

#pragma clang loop unroll(disable)
    for (int step = 0; step < 2048; ++step) {
        const uint4* ab = (const uint4*)hbuf + ((step & 1) << 6) + ((n16 == 1) ? 4 : 0);
        half8 aA = __builtin_bit_cast(half8, ab[0 * 8 + quad]);
        half8 aB = __builtin_bit_cast(half8, ab[1 * 8 + quad]);

        // prefetch next step's gi (latency hides under MFMAs)
        float pr0 = 0.f, pr1 = 0.f, pz0 = 0.f, pz1 = 0.f, pn0 = 0.f, pn1 = 0.f;
        if (step < 2047) {
            const float* gp = gi + (size_t)(step + 1) * 768 + wv * 32 + li;
            pr0 = gp[0]; pr1 = gp[16]; pz0 = gp[256]; pz1 = gp[272]; pn0 = gp[512]; pn1 = gp[528];
        }

        f32x4 acc0 = (f32x4)(0.0f), acc1 = (f32x4)(0.0f), acc2 = (f32x4)(0.0f);
        f32x4 acc3 = (f32x4)(0.0f), acc4 = (f32x4)(0.0f), acc5 = (f32x4)(0.0f);
        MFK(0, aA) aA = __builtin_bit_cast(half8, ab[2 * 8 + quad]);
        MFK(1, aB) aB = __builtin_bit_cast(half8, ab[3 * 8 + quad]);
        MFK(2, aA) aA = __builtin_bit_cast(half8, ab[4 * 8 + quad]);
        MFK(3, aB) aB = __builtin_bit_cast(half8, ab[5 * 8 + quad]);
        MFK(4, aA) aA = __builtin_bit_cast(half8, ab[6 * 8 + quad]);
        MFK(5, aB) aB = __builtin_bit_cast(half8, ab[7 * 8 + quad]);
        MFK(6, aA)
        MFK(7, aB)

        // in-register gates: lane<16 holds cols of its wave's 6 tiles
        if (lane < 16) {
            const float SC = 0.0009765625f;  // 2^-10
            float yr0 = fmaf(acc0.y, SC, acc0.x);
            float yr1 = fmaf(acc1.y, SC, acc1.x);
            float yz0 = fmaf(acc2.y, SC, acc2.x);
            float yz1 = fmaf(acc3.y, SC, acc3.x);
            float yn0 = fmaf(acc4.y, SC, acc4.x) + bn0;
            float yn1 = fmaf(acc5.y, SC, acc5.x) + bn1;
            float r0 = sigm(gr0 + yr0), r1 = sigm(gr1 + yr1);
            float z0 = sigm(gz0 + yz0), z1 = sigm(gz1 + yz1);
            float n0 = tanh_f(fmaf(r0, yn0, gn0v));
            float n1 = tanh_f(fmaf(r1, yn1, gn1v));
            h0 = fmaf(z0, h0 - n0, n0);  // (1-z)*n + z*h
            h1 = fmaf(z1, h1 - n1, n1);
            int wb = (((step + 1) & 1) << 9) + (wv << 6);
            _Float16 h0h = (_Float16)h0, h1h = (_Float16)h1;
            hbuf[wb + li] = h0h;
            hbuf[wb + 32 + li] = (_Float16)((h0 - (float)h0h) * 1024.0f);
            hbuf[wb + 16 + li] = h1h;
            hbuf[wb + 48 + li] = (_Float16)((h1 - (float)h1h) * 1024.0f);
        }
        gr0 = pr0; gr1 = pr1; gz0 = pz0; gz1 = pz1; gn0v = pn0; gn1v = pn1;
        __syncthreads();
    }

    // fused attention head: attn0[j] = sigm(attn_w[j] . h + attn_b[j]), j<64
    // final h is in buffer 0 (2048 even), chunked hi/lo layout
    if (tid < 64) {
        const float* ar = attn_w + tid * 256;
        float acc = attn_b[tid];
        for (int k = 0; k < 256; ++k) {
            int c = k >> 5, i = k & 31;
            float hk = (float)hbuf[c * 64 + i] + (float)hbuf[c * 64 + 32 + i] * 0.0009765625f;
            acc = fmaf(ar[k], hk, acc);
        }
        attn0[tid] = sigm(acc);
    }
}

// ---------------- fuse + linear ----------------
__global__ void k_feat(const float* __restrict__ x3, const float* __restrict__ attn0,
                       const float* __restrict__ lw, const float* __restrict__ lb,
                       float* __restrict__ feat) {
    __shared__ __align__(16) float fused[2304];
    int t = threadIdx.x;  // 64
    for (int i = t; i < 2304; i += 64) fused[i] = x3[i] * attn0[i / 36];
    __syncthreads();
    int row = blockIdx.x * 64 + t;
    const float4* wvv = (const float4*)(lw + (size_t)row * 2304);
    float acc = lb[row];
    for (int i = 0; i < 576; ++i) {
        float4 v = wvv[i];
        const float* f = fused + i * 4;
        acc = fmaf(v.x, f[0], acc);
        acc = fmaf(v.y, f[1], acc);
        acc = fmaf(v.z, f[2], acc);
        acc = fmaf(v.w, f[3], acc);
    }
    feat[row] = fmaxf(acc, 0.0f);
}

// ---------------- LSTM gates ----------------
__global__ void k_lstm_gates(const float* __restrict__ wih, const float* __restrict__ whh,
                             const float* __restrict__ bih, const float* __restrict__ bhh,
                             const float* __restrict__ hx, const float* __restrict__ feat,
                             float* __restrict__ gates) {
    int wid = threadIdx.x >> 6, lane = threadIdx.x & 63;
    int row = blockIdx.x * 4 + wid;
    const float* wi = wih + (size_t)row * 768;
    const float* wh = whh + (size_t)row * 768;
    float acc = 0.0f;
#pragma unroll
    for (int i = 0; i < 12; ++i) {
        int k = lane + i * 64;
        acc = fmaf(wi[k], feat[k & 255], acc);
        acc = fmaf(wh[k], hx[k], acc);
    }
#pragma unroll
    for (int s = 32; s; s >>= 1) acc += __shfl_down(acc, s, 64);
    if (lane == 0) gates[row] = acc + bih[row] + bhh[row];
}

// ---------------- LSTM cell ----------------
__global__ void k_lstm_cell(const float* __restrict__ gates, const float* __restrict__ cx,
                            float* __restrict__ out, float* __restrict__ hxf) {
    int i = threadIdx.x;  // 768
    float g_i = gates[i], g_f = gates[768 + i], g_g = gates[1536 + i], g_o = gates[2304 + i];
    float c = cx[i];
    float cn = sigm(g_f) * c + sigm(g_i) * tanh_f(g_g);
    float hn = sigm(g_o) * tanh_f(cn);
    out[5 + i] = hn;
    out[5 + 768 + i] = cn;
    hxf[i] = hn;
}

// ---------------- heads ----------------
__global__ void k_heads(const float* __restrict__ hxf, const float* __restrict__ temb,
                        const int* __restrict__ tx, const float* __restrict__ cw,
                        const float* __restrict__ cb, const float* __restrict__ aw,
                        const float* __restrict__ ab, float* __restrict__ out) {
    __shared__ float z[800];
    int t = threadIdx.x;  // 320
    for (int i = t; i < 768; i += 320) z[i] = hxf[i];
    if (t < 32) z[768 + t] = temb[tx[0] * 32 + t];
    __syncthreads();
    int w = t >> 6, lane = t & 63;
    const float* row = (w == 0) ? cw : (aw + (size_t)(w - 1) * 800);
    float acc = 0.0f;
    for (int k = lane; k < 800; k += 64) acc = fmaf(row[k], z[k], acc);
#pragma unroll
    for (int s = 32; s; s >>= 1) acc += __shfl_down(acc, s, 64);
    if (lane == 0) {
        float b = (w == 0) ? cb[0] : ab[w - 1];
        out[w] = acc + b;
    }
}

extern "C" void kernel_launch(void* const* d_in, const int* in_sizes, int n_in,
                              void* d_out, int out_size, void* d_ws, size_t ws_size,
                              hipStream_t stream) {
    const float* x = (const float*)d_in[0];
    const int* curr = (const int*)d_in[1];
    const int* tx = (const int*)d_in[4];
    const float* hx = (const float*)d_in[5];
    const float* cx = (const float*)d_in[6];
    const float* c1w = (const float*)d_in[7];
    const float* c1b = (const float*)d_in[8];
    const float* c2w = (const float*)d_in[9];
    const float* c2b = (const float*)d_in[10];
    const float* c3w = (const float*)d_in[11];
    const float* c3b = (const float*)d_in[12];
    const float* emb = (const float*)d_in[13];
    const float* temb = (const float*)d_in[14];
    const float* gwih = (const float*)d_in[15];
    const float* gwhh = (const float*)d_in[16];
    const float* gbih = (const float*)d_in[17];
    const float* gbhh = (const float*)d_in[18];
    const float* attw = (const float*)d_in[19];
    const float* attb = (const float*)d_in[20];
    const float* linw = (const float*)d_in[21];
    const float* linb = (const float*)d_in[22];
    const float* lwih = (const float*)d_in[23];
    const float* lwhh = (const float*)d_in[24];
    const float* lbih = (const float*)d_in[25];
    const float* lbhh = (const float*)d_in[26];
    const float* cw = (const float*)d_in[27];
    const float* cb = (const float*)d_in[28];
    const float* aw = (const float*)d_in[29];
    const float* ab = (const float*)d_in[30];
    float* out = (float*)d_out;

    char* ws = (char*)d_ws;
    float* gi = (float*)(ws + 0);                 // 2048*768 f32
    float* h1 = (float*)(ws + 6291456);
    float* h2 = (float*)(ws + 6752256);
    float* x3 = (float*)(ws + 6802432);
    float* attn0 = (float*)(ws + 6811648);
    float* feat = (float*)(ws + 6811904);
    float* gates = (float*)(ws + 6812928);
    float* hxf = (float*)(ws + 6825216);
    uint32_t* wf16p = (uint32_t*)(ws + 6828288);  // 98304 u32 (f16-pair W_hh)

    k_pack<<<384, 256, 0, stream>>>(gwhh, wf16p);
    k_gi<<<6144, 256, 0, stream>>>(curr, emb, gwih, gbih, gbhh, gi);
    k_conv1<<<450, 256, 0, stream>>>(x, c1w, c1b, h1);
    k_conv2<<<49, 256, 0, stream>>>(h1, c2w, c2b, h2);
    k_conv3<<<9, 256, 0, stream>>>(h2, c3w, c3b, x3);
    k_gru_scan<<<1, 512, 0, stream>>>(gi, wf16p, gbhh, attw, attb, attn0);
    k_feat<<<4, 64, 0, stream>>>(x3, attn0, linw, linb, feat);
    k_lstm_gates<<<768, 256, 0, stream>>>(lwih, lwhh, lbih, lbhh, hx, feat, gates);
    k_lstm_cell<<<1, 768, 0, stream>>>(gates, cx, out, hxf);
    k_heads<<<1, 320, 0, stream>>>(hxf, temb, tx, cw, cb, aw, ab, out);
}